// Round 15
// baseline (5287.944 us; speedup 1.0000x reference)
//
#include <hip/hip_runtime.h>
#include <math.h>

#define B_   8
#define L_   2048
#define E_   768
#define H_   512
#define G4_  2048   // 4*H
#define CL_  512    // L chunk length

static __device__ __forceinline__ float sigm(float x){ return 1.0f/(1.0f+expf(-x)); }
static __device__ __forceinline__ float ftanh(float x){
  float ax = fabsf(x);
  float e  = expf(2.0f*ax);            // inf for large ax -> r = 1
  float r  = 1.0f - 2.0f/(e+1.0f);
  return copysignf(r, x);
}

// ---------------------------------------------------------------------------
// GEMM body: C[crow(r)][N] = A'[r,:K] . W[n,:K]^T + bias1 (+bias2)
// A row map: ab=r/CL, al=r%CL, arow=ab*Ltot+c0+al  (batch-chunk gather)
// C row map: cb=r/CLc, cl=r%CLc, crow=cb*Ltotc+c0c+cl (scatter for partial L)
// 128x128 tile, BK=16, 256 threads, 8x8 micro tile.
// ---------------------------------------------------------------------------
__device__ __forceinline__ void gemm_body(
    const float* __restrict__ A, const float* __restrict__ W,
    const float* __restrict__ bias1, const float* __restrict__ bias2,
    float* __restrict__ C, int N, int K, int CL, int Ltot, int c0,
    int CLc, int Ltotc, int c0c, int bm, int bn)
{
  __shared__ float As[16][132];
  __shared__ float Bs[16][132];
  const int tid = threadIdx.x;

  const int r  = tid >> 1;          // 0..127 (loader row)
  const int kq = (tid & 1) * 8;     // 0 or 8 (loader k-offset)
  const int am = bm + r;
  const int ab = am / CL, al = am % CL;
  const float* Arow = A + ((size_t)ab * Ltot + c0 + al) * K;
  const float* Wrow = W + (size_t)(bn + r) * K;

  const int tx = tid & 15, ty = tid >> 4;
  float acc[8][8] = {};

  for (int k0 = 0; k0 < K; k0 += 16) {
    float4 a0 = *(const float4*)(Arow + k0 + kq);
    float4 a1 = *(const float4*)(Arow + k0 + kq + 4);
    float4 w0 = *(const float4*)(Wrow + k0 + kq);
    float4 w1 = *(const float4*)(Wrow + k0 + kq + 4);
    __syncthreads();
    As[kq+0][r]=a0.x; As[kq+1][r]=a0.y; As[kq+2][r]=a0.z; As[kq+3][r]=a0.w;
    As[kq+4][r]=a1.x; As[kq+5][r]=a1.y; As[kq+6][r]=a1.z; As[kq+7][r]=a1.w;
    Bs[kq+0][r]=w0.x; Bs[kq+1][r]=w0.y; Bs[kq+2][r]=w0.z; Bs[kq+3][r]=w0.w;
    Bs[kq+4][r]=w1.x; Bs[kq+5][r]=w1.y; Bs[kq+6][r]=w1.z; Bs[kq+7][r]=w1.w;
    __syncthreads();
    #pragma unroll
    for (int k = 0; k < 16; ++k) {
      float4 x0 = *(const float4*)&As[k][ty*4];
      float4 x1 = *(const float4*)&As[k][64 + ty*4];
      float4 y0 = *(const float4*)&Bs[k][tx*4];
      float4 y1 = *(const float4*)&Bs[k][64 + tx*4];
      float av[8] = {x0.x,x0.y,x0.z,x0.w, x1.x,x1.y,x1.z,x1.w};
      float bv[8] = {y0.x,y0.y,y0.z,y0.w, y1.x,y1.y,y1.z,y1.w};
      #pragma unroll
      for (int i=0;i<8;++i)
        #pragma unroll
        for (int j=0;j<8;++j)
          acc[i][j] += av[i]*bv[j];
    }
  }

  float bs[8];
  #pragma unroll
  for (int j=0;j<4;++j) {
    int c0n = bn + tx*4 + j, c1n = bn + 64 + tx*4 + j;
    bs[j]   = bias1[c0n] + (bias2 ? bias2[c0n] : 0.0f);
    bs[4+j] = bias1[c1n] + (bias2 ? bias2[c1n] : 0.0f);
  }
  #pragma unroll
  for (int i=0;i<8;++i) {
    int r0 = bm + ((i<4) ? (ty*4+i) : (64 + ty*4 + (i-4)));
    int cb = r0 / CLc, cl = r0 % CLc;
    size_t crow = (size_t)cb * Ltotc + c0c + cl;
    float4 o0 = { acc[i][0]+bs[0], acc[i][1]+bs[1], acc[i][2]+bs[2], acc[i][3]+bs[3] };
    float4 o1 = { acc[i][4]+bs[4], acc[i][5]+bs[5], acc[i][6]+bs[6], acc[i][7]+bs[7] };
    *(float4*)&C[crow*N + bn + tx*4]      = o0;
    *(float4*)&C[crow*N + bn + 64 + tx*4] = o1;
  }
}

__global__ __launch_bounds__(256) void gemm128(
    const float* __restrict__ A, const float* __restrict__ W,
    const float* __restrict__ bias1, const float* __restrict__ bias2,
    float* __restrict__ C, int N, int K, int CL, int Ltot, int c0,
    int CLc, int Ltotc, int c0c)
{
  gemm_body(A, W, bias1, bias2, C, N, K, CL, Ltot, c0, CLc, Ltotc, c0c,
            blockIdx.y*128, blockIdx.x*128);
}

// ---------------------------------------------------------------------------
// Recurrence v15: wave-decoupled partial-FMA. Same tagged-u64 relaxed-agent
// exchange as r5/r14 (the measured floor); the change is INTRA-block:
// wave w polls EXACTLY the 128 h-columns [128w,128w+128) its FMA consumes
// (same 2*tid word indexing as r5), stages wave-privately (wave-ordered
// reuse, no parity), wave_barrier, then computes its 128-col partial for all
// 64 gate-rows (lane = gate g, row r; weights streamed from L2, h reads are
// LDS broadcast). The single BLOCK barrier moves AFTER the partial FMA, so
// fast waves compute while the straggler wave still polls — FMA skew hidden,
// post-last-arrival path = {own-slice FMA, barrier, 16-val combine, act,
// publish}. part[] is parity-double-buffered (same induction as r5's hsh).
// Activation spread 4 lanes/wave; Xp prefetched per act-thread in registers.
// ---------------------------------------------------------------------------
__device__ __forceinline__ void recur_body(
    const float* __restrict__ Xp, const float* __restrict__ Whh,
    float* __restrict__ enc_out, unsigned long long* __restrict__ hb2,
    float* __restrict__ cbuf, float* __restrict__ hT, int t0, int nsteps)
{
  const int tid  = threadIdx.x;
  const int w    = tid >> 6;           // wave 0..3 (h-column slice)
  const int lane = tid & 63;
  const int b    = blockIdx.x >> 5;    // batch 0..7
  const int m    = blockIdx.x & 31;    // h-slice 0..31
  const int j0   = m*16;
  const int g    = lane >> 4;          // gate 0..3
  const int r    = lane & 15;          // row-within-slice 0..15

  __shared__ float hws[4][128];        // wave-private h slice (1 KB/wave)
  __shared__ float part[2][4][64];     // parity x wave x gate-row partials

  // act threads: lanes 0..3 of each wave own local h-index ai = w*4+lane
  const bool isAct = (lane < 4);
  const int  ai    = w*4 + lane;       // 0..15
  const int  aj    = j0 + ai;          // global h index

  float cc = 0.0f;
  float xn0=0.f, xn1=0.f, xn2=0.f, xn3=0.f;
  if (isAct) {
    cc = cbuf[b*H_ + aj];
    const float* xp = Xp + ((size_t)(b*CL_ + 0))*G4_ + aj;
    xn0 = xp[0]; xn1 = xp[H_]; xn2 = xp[2*H_]; xn3 = xp[3*H_];
  }

  // this lane's weight row: gate g, h-row j0+r, column slice [128w, 128w+128)
  const float* wrow = Whh + ((size_t)(g*H_ + j0 + r))*H_ + 128*w;

  for (int s = 0; s < nsteps; ++s) {
    const int t = t0 + s;
    const unsigned ut = (unsigned)t;
    const int p = s & 1;

    // ---- poll own 2 words (cols 128w+2lane, +1) until tag == t ----
    {
      const unsigned long long* src =
          hb2 + ((size_t)(t & 1))*(B_*H_) + (size_t)b*H_ + tid*2;
      unsigned long long v0 = 0, v1 = 0;
      bool d0 = false, d1 = false;
      do {
        if (!d0) v0 = __hip_atomic_load(src,   __ATOMIC_RELAXED, __HIP_MEMORY_SCOPE_AGENT);
        if (!d1) v1 = __hip_atomic_load(src+1, __ATOMIC_RELAXED, __HIP_MEMORY_SCOPE_AGENT);
        d0 = d0 || ((unsigned)(v0 >> 32) == ut);
        d1 = d1 || ((unsigned)(v1 >> 32) == ut);
      } while (!(d0 && d1));
      union { unsigned u; float f; } u0, u1;
      u0.u = (unsigned)v0; u1.u = (unsigned)v1;
      hws[w][2*lane]   = u0.f;
      hws[w][2*lane+1] = u1.f;
    }
    __builtin_amdgcn_wave_barrier();   // wave-local write->read order

    // ---- partial FMA over own 128-col slice (h = LDS broadcast) ----
    float a0=0.f, a1=0.f, a2=0.f, a3=0.f;
    #pragma unroll
    for (int k = 0; k < 8; ++k) {
      float4 h0 = ((const float4*)hws[w])[4*k+0];
      float4 h1 = ((const float4*)hws[w])[4*k+1];
      float4 h2 = ((const float4*)hws[w])[4*k+2];
      float4 h3 = ((const float4*)hws[w])[4*k+3];
      float4 w0 = ((const float4*)wrow)[4*k+0];
      float4 w1 = ((const float4*)wrow)[4*k+1];
      float4 w2 = ((const float4*)wrow)[4*k+2];
      float4 w3 = ((const float4*)wrow)[4*k+3];
      a0 = fmaf(w0.x,h0.x, fmaf(w0.y,h0.y, fmaf(w0.z,h0.z, fmaf(w0.w,h0.w, a0))));
      a1 = fmaf(w1.x,h1.x, fmaf(w1.y,h1.y, fmaf(w1.z,h1.z, fmaf(w1.w,h1.w, a1))));
      a2 = fmaf(w2.x,h2.x, fmaf(w2.y,h2.y, fmaf(w2.z,h2.z, fmaf(w2.w,h2.w, a2))));
      a3 = fmaf(w3.x,h3.x, fmaf(w3.y,h3.y, fmaf(w3.z,h3.z, fmaf(w3.w,h3.w, a3))));
    }
    part[p][w][lane] = (a0+a1) + (a2+a3);
    __syncthreads();                   // the ONLY block barrier (post-FMA)

    // ---- combine + activation + publish on 16 spread act threads ----
    if (isAct) {
      float G0 = part[p][0][ 0+ai] + part[p][1][ 0+ai] + part[p][2][ 0+ai] + part[p][3][ 0+ai];
      float G1 = part[p][0][16+ai] + part[p][1][16+ai] + part[p][2][16+ai] + part[p][3][16+ai];
      float G2 = part[p][0][32+ai] + part[p][1][32+ai] + part[p][2][32+ai] + part[p][3][32+ai];
      float G3 = part[p][0][48+ai] + part[p][1][48+ai] + part[p][2][48+ai] + part[p][3][48+ai];
      float g0 = G0 + xn0, g1 = G1 + xn1, g2 = G2 + xn2, g3 = G3 + xn3;
      cc = sigm(g1)*cc + sigm(g0)*ftanh(g2);
      float hn = sigm(g3)*ftanh(cc);
      union { float f; unsigned u; } hu; hu.f = hn;
      unsigned long long wv =
          (((unsigned long long)(ut + 1u)) << 32) | (unsigned long long)hu.u;
      __hip_atomic_store(hb2 + ((size_t)((t+1) & 1))*(B_*H_) + (size_t)b*H_ + aj, wv,
                         __ATOMIC_RELAXED, __HIP_MEMORY_SCOPE_AGENT);
      enc_out[((size_t)b*L_ + t)*H_ + aj] = hn;
      if (t == L_ - 1) hT[b*H_ + aj] = hn;
      if (s + 1 < nsteps) {            // prefetch next Xp slice (hidden)
        const float* xp = Xp + ((size_t)(b*CL_ + s + 1))*G4_ + aj;
        xn0 = xp[0]; xn1 = xp[H_]; xn2 = xp[2*H_]; xn3 = xp[3*H_];
      }
    }
  }
  if (isAct) cbuf[b*H_ + aj] = cc;
}

// ---------------------------------------------------------------------------
// Fused launch: blocks [0,256) = recurrence chunk; blocks [256,256+ngemm) =
// concurrent GEMM (next chunk's Xproj, or ctx for finalized ENC rows).
// launch_bounds(256,1) — (256,4) spilled the recur path in r13.
// Recur blocks have the lowest IDs (dispatched resident first); GEMM blocks
// never wait on recur -> no deadlock possible, worst case lost overlap.
// ---------------------------------------------------------------------------
__global__ __launch_bounds__(256, 1) void fused_rg(
    const float* __restrict__ Xp, const float* __restrict__ Whh,
    float* __restrict__ enc_out, unsigned long long* __restrict__ hb2,
    float* __restrict__ cbuf, float* __restrict__ hT, int t0, int nsteps,
    const float* __restrict__ A, const float* __restrict__ W,
    const float* __restrict__ bias1, const float* __restrict__ bias2,
    float* __restrict__ C, int gN, int gK, int gCL, int gLtot, int gc0,
    int gCLc, int gLtotc, int gc0c, int gbx)
{
  if ((int)blockIdx.x < 256) {
    recur_body(Xp, Whh, enc_out, hb2, cbuf, hT, t0, nsteps);
  } else {
    const int b2 = (int)blockIdx.x - 256;
    gemm_body(A, W, bias1, bias2, C, gN, gK, gCL, gLtot, gc0,
              gCLc, gLtotc, gc0c, (b2 / gbx) * 128, (b2 % gbx) * 128);
  }
}

// ---------------------------------------------------------------------------
// out[b][n] = act( x1[b].W1[n,:K1] + (x2? x2[b].W2[n,:K2]) + bias1[n] (+bias2) )
// ---------------------------------------------------------------------------
__global__ __launch_bounds__(256) void dual_mv(
    const float* __restrict__ x1, const float* __restrict__ W1, int ld1, int K1,
    const float* __restrict__ x2, const float* __restrict__ W2, int ld2, int K2,
    const float* __restrict__ bias1, const float* __restrict__ bias2,
    float* __restrict__ out, int N, int act)
{
  const int w = blockIdx.x*4 + (threadIdx.x>>6);
  const int lane = threadIdx.x & 63;
  const int b = w / N, n = w % N;
  float s = 0.0f;
  for (int k = lane*4; k < K1; k += 256) {
    float4 xv = *(const float4*)(x1 + (size_t)b*K1 + k);
    float4 wv = *(const float4*)(W1 + (size_t)n*ld1 + k);
    s += xv.x*wv.x + xv.y*wv.y + xv.z*wv.z + xv.w*wv.w;
  }
  if (x2) {
    for (int k = lane*4; k < K2; k += 256) {
      float4 xv = *(const float4*)(x2 + (size_t)b*K2 + k);
      float4 wv = *(const float4*)(W2 + (size_t)n*ld2 + k);
      s += xv.x*wv.x + xv.y*wv.y + xv.z*wv.z + xv.w*wv.w;
    }
  }
  #pragma unroll
  for (int m=32; m>0; m>>=1) s += __shfl_xor(s, m, 64);
  if (lane == 0) {
    float r = s + bias1[n] + (bias2 ? bias2[n] : 0.0f);
    if (act) r = tanhf(r);
    out[(size_t)b*N + n] = r;
  }
}

__global__ void dec_cell(const float* __restrict__ g, float* __restrict__ c,
                         float* __restrict__ ht)
{
  int i = blockIdx.x*256 + threadIdx.x;     // 4096 threads
  int b = i >> 9, j = i & 511;
  const float* gb = g + (size_t)b*G4_;
  float gi_ = gb[j], gf = gb[H_+j], gg = gb[2*H_+j], go = gb[3*H_+j];
  float cc = c[i];
  cc = sigm(gf)*cc + sigm(gi_)*tanhf(gg);
  ht[i] = sigm(go)*tanhf(cc);
  c[i]  = cc;
}

__global__ __launch_bounds__(256) void dec_att(
    const float* __restrict__ inp, const float* __restrict__ ctx,
    const float* __restrict__ V, float* __restrict__ att)
{
  const int w = blockIdx.x*4 + (threadIdx.x>>6);  // w = b*L_ + l
  const int lane = threadIdx.x & 63;
  const int b = w >> 11;
  const float* cr = ctx + (size_t)w*H_;
  const float* ip = inp + (size_t)b*H_;
  float s = 0.0f;
  #pragma unroll
  for (int i=0;i<2;++i) {
    int k = lane*4 + i*256;
    float4 c4 = *(const float4*)(cr+k);
    float4 i4 = *(const float4*)(ip+k);
    float4 v4 = *(const float4*)(V+k);
    s += v4.x*tanhf(i4.x+c4.x) + v4.y*tanhf(i4.y+c4.y)
       + v4.z*tanhf(i4.z+c4.z) + v4.w*tanhf(i4.w+c4.w);
  }
  #pragma unroll
  for (int m=32; m>0; m>>=1) s += __shfl_xor(s, m, 64);
  if (lane == 0) att[w] = s;
}

__global__ __launch_bounds__(256) void dec_softmax(
    const float* __restrict__ att, const float* __restrict__ enc,
    int iter, int* __restrict__ chosen,
    float* __restrict__ out_alpha, float* __restrict__ out_ptr,
    float* __restrict__ x_next)
{
  const int b = blockIdx.x, tid = threadIdx.x;
  __shared__ float rv[256]; __shared__ int ri[256];
  __shared__ float s_mx, s_sum; __shared__ int s_idx;
  const int banned = iter ? chosen[b] : -1;
  float a[8]; float mx = -INFINITY;
  #pragma unroll
  for (int i=0;i<8;++i) {
    int l = (i<<8)+tid;
    float v = att[(size_t)b*L_ + l];
    if (l == banned) v = -INFINITY;
    a[i] = v; mx = fmaxf(mx, v);
  }
  rv[tid]=mx; __syncthreads();
  for (int s=128;s>0;s>>=1){ if (tid<s) rv[tid]=fmaxf(rv[tid],rv[tid+s]); __syncthreads(); }
  if (tid==0) s_mx = rv[0];
  __syncthreads();
  const float MX = s_mx;
  __syncthreads();
  float sum = 0.0f;
  #pragma unroll
  for (int i=0;i<8;++i) {
    int l = (i<<8)+tid;
    float pexp = (l == banned) ? 0.0f : expf(a[i]-MX);
    sum += pexp; a[i] = pexp;
  }
  rv[tid]=sum; __syncthreads();
  for (int s=128;s>0;s>>=1){ if (tid<s) rv[tid]+=rv[tid+s]; __syncthreads(); }
  if (tid==0) s_sum = rv[0];
  __syncthreads();
  const float inv = 1.0f/s_sum;
  __syncthreads();
  // argmax (first-occurrence on ties, matches jnp.argmax)
  float vb = -1.0f; int ib = 1<<30;
  #pragma unroll
  for (int i=0;i<8;++i) {
    int l = (i<<8)+tid;
    if (l != banned) { float v = a[i]; if (v > vb || (v == vb && l < ib)) { vb=v; ib=l; } }
  }
  rv[tid]=vb; ri[tid]=ib; __syncthreads();
  for (int s=128;s>0;s>>=1) {
    if (tid<s) {
      float v2=rv[tid+s]; int i2=ri[tid+s];
      if (v2 > rv[tid] || (v2 == rv[tid] && i2 < ri[tid])) { rv[tid]=v2; ri[tid]=i2; }
    }
    __syncthreads();
  }
  if (tid==0) {
    s_idx = ri[0];
    out_ptr[b*2+iter] = (float)ri[0];
    if (iter==0) chosen[b] = ri[0];
  }
  __syncthreads();
  #pragma unroll
  for (int i=0;i<8;++i) {
    int l = (i<<8)+tid;
    out_alpha[((size_t)b*2+iter)*L_ + l] = a[i]*inv;
  }
  const int idx = s_idx;
  for (int j=tid; j<H_; j+=256)
    x_next[(size_t)b*H_ + j] = enc[((size_t)b*L_ + idx)*H_ + j];
}

__global__ void dec_hidden1(const float* __restrict__ ctx, const float* __restrict__ alpha_all,
                            int iter, float* __restrict__ part)
{
  const int b = blockIdx.x >> 4, ch = blockIdx.x & 15;
  const int j = threadIdx.x;  // 512
  const float* al = alpha_all + ((size_t)b*2+iter)*L_ + ch*128;
  const float* cp = ctx + ((size_t)b*L_ + ch*128)*H_ + j;
  float s = 0.0f;
  for (int l=0; l<128; ++l) s += cp[(size_t)l*H_] * al[l];
  part[((size_t)b*16+ch)*H_ + j] = s;
}

__global__ void dec_hidden2(const float* __restrict__ part, float* __restrict__ hid)
{
  int i = blockIdx.x*256 + threadIdx.x;  // 4096
  int b = i >> 9, j = i & 511;
  float s = 0.0f;
  #pragma unroll
  for (int ch=0; ch<16; ++ch) s += part[((size_t)b*16+ch)*H_ + j];
  hid[i] = s;
}

// ---------------------------------------------------------------------------
extern "C" void kernel_launch(void* const* d_in, const int* in_sizes, int n_in,
                              void* d_out, int out_size, void* d_ws, size_t ws_size,
                              hipStream_t stream)
{
  const float* emb   = (const float*)d_in[0];
  const float* x0    = (const float*)d_in[1];
  const float* W_ih  = (const float*)d_in[2];
  const float* W_hh  = (const float*)d_in[3];
  const float* b_ih  = (const float*)d_in[4];
  const float* b_hh  = (const float*)d_in[5];
  const float* Wd_in = (const float*)d_in[6];
  const float* bd_in = (const float*)d_in[7];
  const float* Wd_hh = (const float*)d_in[8];
  const float* bd_hh = (const float*)d_in[9];
  const float* W_inp = (const float*)d_in[10];
  const float* b_inp = (const float*)d_in[11];
  const float* Wc    = (const float*)d_in[12];
  const float* bc    = (const float*)d_in[13];
  const float* V     = (const float*)d_in[14];
  const float* W_out = (const float*)d_in[15];
  const float* b_out = (const float*)d_in[16];

  const size_t BIG = 8388608;  // floats per XP/ENC buffer
  const size_t tail_floats = 8192*2 /*HB2*/ + 4096 + 4096 + 16384 + 4096*4 + 16384 + 65536 + 64;
  const bool dbuf = ws_size >= (3*BIG + tail_floats) * sizeof(float);

  float* ws  = (float*)d_ws;
  float* XPA = ws;                               // 8,388,608 floats; also CTX
  float* XPB = dbuf ? (XPA + BIG) : XPA;         // second Xproj buffer
  float* ENC = (dbuf ? XPB : XPA) + BIG;         // 8,388,608 floats
  unsigned long long* HB2 = (unsigned long long*)(ENC + BIG); // 8192 u64
  float* HB  = (float*)(HB2 + 8192);             // 4096 (h_T)
  float* CB  = HB + 4096;                        // 4096 (c state)
  float* DG  = CB + 4096;                        // 16384
  float* HT  = DG + 16384;                       // 4096
  float* INP = HT + 4096;                        // 4096
  float* ATT = INP + 4096;                       // 16384
  float* HID = ATT + 16384;                      // 4096
  float* XN  = HID + 4096;                       // 4096
  float* HD  = XN + 4096;                        // 4096
  float* PART = HD + 4096;                       // 65536
  int* CHOSEN = (int*)(PART + 65536);            // 8
  float* CTX = XPA;

  // zero tagged h buffer (tag0 = h0=0), h_T, c0 — contiguous region
  hipMemsetAsync(HB2, 0, 8192*sizeof(unsigned long long) + (4096+4096)*sizeof(float), stream);

  if (dbuf) {
    // 1. Xproj chunk0 -> XPA (exposed)
    gemm128<<<dim3(G4_/128, (B_*CL_)/128), 256, 0, stream>>>(
        emb, W_ih, b_ih, b_hh, XPA, G4_, E_, CL_, L_, 0*CL_, 1<<30, 0, 0);
    // 2-4. recur(chunk c) || Xproj(chunk c+1) into the other buffer
    float* xpsrc = XPA; float* xpdst = XPB;
    for (int c = 0; c < 3; ++c) {
      fused_rg<<<256 + 512, 256, 0, stream>>>(
          xpsrc, W_hh, ENC, HB2, CB, HB, c*CL_, CL_,
          emb, W_ih, b_ih, b_hh, xpdst, G4_, E_, CL_, L_, (c+1)*CL_,
          1<<30, 0, 0, /*gbx=*/16);
      float* tmp = xpsrc; xpsrc = xpdst; xpdst = tmp;
    }
    // 5. recur(chunk3) || ctx rows l<1536 (ENC chunks 0-2 finalized) -> CTX
    fused_rg<<<256 + 384, 256, 0, stream>>>(
        xpsrc, W_hh, ENC, HB2, CB, HB, 3*CL_, CL_,
        ENC, Wc, bc, nullptr, CTX, H_, H_, 1536, L_, 0,
        1536, L_, 0, /*gbx=*/4);
    // 6. ctx rows l in [1536,2048) (exposed, small)
    gemm128<<<dim3(H_/128, (B_*CL_)/128), 256, 0, stream>>>(
        ENC, Wc, bc, nullptr, CTX, H_, H_, CL_, L_, 1536, CL_, L_, 1536);
  } else {
    // serial fallback
    for (int c = 0; c < 4; ++c) {
      gemm128<<<dim3(G4_/128, (B_*CL_)/128), 256, 0, stream>>>(
          emb, W_ih, b_ih, b_hh, XPA, G4_, E_, CL_, L_, c*CL_, 1<<30, 0, 0);
      fused_rg<<<256, 256, 0, stream>>>(
          XPA, W_hh, ENC, HB2, CB, HB, c*CL_, CL_,
          nullptr, nullptr, nullptr, nullptr, nullptr, 0, 0, 1, 1, 0, 1, 1, 0, 1);
    }
    gemm128<<<dim3(H_/128, (B_*L_)/128), 256, 0, stream>>>(
        ENC, Wc, bc, nullptr, CTX, H_, H_, L_, L_, 0, 1<<30, 0, 0);
  }

  // ---- decoder: 2 pointer steps ----
  float* out = (float*)d_out;
  const float* x_cur = x0;
  const float* h_cur = HB;
  for (int iter=0; iter<2; ++iter) {
    dual_mv<<<(B_*G4_)/4, 256, 0, stream>>>(x_cur, Wd_in, H_, H_,
                                            h_cur, Wd_hh, H_, H_,
                                            bd_in, bd_hh, DG, G4_, 0);
    dec_cell<<<16, 256, 0, stream>>>(DG, CB, HT);
    dual_mv<<<(B_*H_)/4, 256, 0, stream>>>(HT, W_inp, H_, H_,
                                           nullptr, nullptr, 0, 0,
                                           b_inp, nullptr, INP, H_, 0);
    dec_att<<<(B_*L_)/4, 256, 0, stream>>>(INP, CTX, V, ATT);
    dec_softmax<<<B_, 256, 0, stream>>>(ATT, ENC, iter, CHOSEN, out, out + 32768, XN);
    dec_hidden1<<<B_*16, 512, 0, stream>>>(CTX, out, iter, PART);
    dec_hidden2<<<16, 256, 0, stream>>>(PART, HID);
    dual_mv<<<(B_*H_)/4, 256, 0, stream>>>(HID, W_out, 2*H_, H_,
                                           HT, W_out + H_, 2*H_, H_,
                                           b_out, nullptr, HD, H_, 1);
    x_cur = XN; h_cur = HD;
  }
}

// Round 16
// 4873.634 us; speedup vs baseline: 1.0850x; 1.0850x over previous
//
#include <hip/hip_runtime.h>
#include <math.h>

#define B_   8
#define L_   2048
#define E_   768
#define H_   512
#define G4_  2048   // 4*H
#define CL_  512    // L chunk length

static __device__ __forceinline__ float sigm(float x){ return 1.0f/(1.0f+expf(-x)); }
static __device__ __forceinline__ float ftanh(float x){
  float ax = fabsf(x);
  float e  = expf(2.0f*ax);            // inf for large ax -> r = 1
  float r  = 1.0f - 2.0f/(e+1.0f);
  return copysignf(r, x);
}

// ---------------------------------------------------------------------------
// GEMM body: C[crow(r)][N] = A'[r,:K] . W[n,:K]^T + bias1 (+bias2)
// A row map: ab=r/CL, al=r%CL, arow=ab*Ltot+c0+al  (batch-chunk gather)
// C row map: cb=r/CLc, cl=r%CLc, crow=cb*Ltotc+c0c+cl (scatter for partial L)
// 128x128 tile, BK=16, 256 threads, 8x8 micro tile.
// ---------------------------------------------------------------------------
__device__ __forceinline__ void gemm_body(
    const float* __restrict__ A, const float* __restrict__ W,
    const float* __restrict__ bias1, const float* __restrict__ bias2,
    float* __restrict__ C, int N, int K, int CL, int Ltot, int c0,
    int CLc, int Ltotc, int c0c, int bm, int bn)
{
  __shared__ float As[16][132];
  __shared__ float Bs[16][132];
  const int tid = threadIdx.x;

  const int r  = tid >> 1;          // 0..127 (loader row)
  const int kq = (tid & 1) * 8;     // 0 or 8 (loader k-offset)
  const int am = bm + r;
  const int ab = am / CL, al = am % CL;
  const float* Arow = A + ((size_t)ab * Ltot + c0 + al) * K;
  const float* Wrow = W + (size_t)(bn + r) * K;

  const int tx = tid & 15, ty = tid >> 4;
  float acc[8][8] = {};

  for (int k0 = 0; k0 < K; k0 += 16) {
    float4 a0 = *(const float4*)(Arow + k0 + kq);
    float4 a1 = *(const float4*)(Arow + k0 + kq + 4);
    float4 w0 = *(const float4*)(Wrow + k0 + kq);
    float4 w1 = *(const float4*)(Wrow + k0 + kq + 4);
    __syncthreads();
    As[kq+0][r]=a0.x; As[kq+1][r]=a0.y; As[kq+2][r]=a0.z; As[kq+3][r]=a0.w;
    As[kq+4][r]=a1.x; As[kq+5][r]=a1.y; As[kq+6][r]=a1.z; As[kq+7][r]=a1.w;
    Bs[kq+0][r]=w0.x; Bs[kq+1][r]=w0.y; Bs[kq+2][r]=w0.z; Bs[kq+3][r]=w0.w;
    Bs[kq+4][r]=w1.x; Bs[kq+5][r]=w1.y; Bs[kq+6][r]=w1.z; Bs[kq+7][r]=w1.w;
    __syncthreads();
    #pragma unroll
    for (int k = 0; k < 16; ++k) {
      float4 x0 = *(const float4*)&As[k][ty*4];
      float4 x1 = *(const float4*)&As[k][64 + ty*4];
      float4 y0 = *(const float4*)&Bs[k][tx*4];
      float4 y1 = *(const float4*)&Bs[k][64 + tx*4];
      float av[8] = {x0.x,x0.y,x0.z,x0.w, x1.x,x1.y,x1.z,x1.w};
      float bv[8] = {y0.x,y0.y,y0.z,y0.w, y1.x,y1.y,y1.z,y1.w};
      #pragma unroll
      for (int i=0;i<8;++i)
        #pragma unroll
        for (int j=0;j<8;++j)
          acc[i][j] += av[i]*bv[j];
    }
  }

  float bs[8];
  #pragma unroll
  for (int j=0;j<4;++j) {
    int c0n = bn + tx*4 + j, c1n = bn + 64 + tx*4 + j;
    bs[j]   = bias1[c0n] + (bias2 ? bias2[c0n] : 0.0f);
    bs[4+j] = bias1[c1n] + (bias2 ? bias2[c1n] : 0.0f);
  }
  #pragma unroll
  for (int i=0;i<8;++i) {
    int r0 = bm + ((i<4) ? (ty*4+i) : (64 + ty*4 + (i-4)));
    int cb = r0 / CLc, cl = r0 % CLc;
    size_t crow = (size_t)cb * Ltotc + c0c + cl;
    float4 o0 = { acc[i][0]+bs[0], acc[i][1]+bs[1], acc[i][2]+bs[2], acc[i][3]+bs[3] };
    float4 o1 = { acc[i][4]+bs[4], acc[i][5]+bs[5], acc[i][6]+bs[6], acc[i][7]+bs[7] };
    *(float4*)&C[crow*N + bn + tx*4]      = o0;
    *(float4*)&C[crow*N + bn + 64 + tx*4] = o1;
  }
}

__global__ __launch_bounds__(256) void gemm128(
    const float* __restrict__ A, const float* __restrict__ W,
    const float* __restrict__ bias1, const float* __restrict__ bias2,
    float* __restrict__ C, int N, int K, int CL, int Ltot, int c0,
    int CLc, int Ltotc, int c0c)
{
  gemm_body(A, W, bias1, bias2, C, N, K, CL, Ltot, c0, CLc, Ltotc, c0c,
            blockIdx.y*128, blockIdx.x*128);
}

// ---------------------------------------------------------------------------
// Recurrence body = r5 champion VERBATIM (1245 us/dispatch, 2.43 us/step —
// best of 8 protocol variants r2..r11 and 2 intra-block schedules; the
// MALL round-trip (publish visibility + probe detect) is the floor).
// ---------------------------------------------------------------------------
__device__ __forceinline__ void recur_body(
    const float* __restrict__ Xp, const float* __restrict__ Whh,
    float* __restrict__ enc_out, unsigned long long* __restrict__ hb2,
    float* __restrict__ cbuf, float* __restrict__ hT, int t0, int nsteps)
{
  const int tid = threadIdx.x;
  const int b   = blockIdx.x >> 5;     // batch 0..7
  const int m   = blockIdx.x & 31;     // h-slice 0..31
  const int c   = tid >> 4;            // cluster 0..15
  const int q   = tid & 15;            // lane within cluster
  const int j   = m*16 + c;            // owned h index

  __shared__ float hsh[2][512];
  __shared__ float xpsh[2][64];

  // weights: 4 gates x 1 row x 32 cols per thread (compiler streams via L2)
  float4 w4[4][8];
  #pragma unroll
  for (int gi = 0; gi < 4; ++gi) {
    const float* wr = Whh + ((size_t)(gi*H_ + j))*H_ + q*4;
    #pragma unroll
    for (int k = 0; k < 8; ++k) w4[gi][k] = *(const float4*)(wr + k*64);
  }
  float cc = 0.0f;
  if (q == 0) cc = cbuf[b*H_ + j];

  float xv = 0.0f;
  if (tid < 64)
    xv = Xp[((size_t)(b*CL_ + 0))*G4_ + (size_t)(tid>>4)*H_ + m*16 + (tid&15)];

  const bool own = ((tid >> 3) == m);  // this thread's 2 words are block-own

  for (int s = 0; s < nsteps; ++s) {
    const int t = t0 + s;
    const int p = s & 1;

    if (tid < 64) {
      xpsh[p][tid] = xv;
      if (s + 1 < nsteps)
        xv = Xp[((size_t)(b*CL_ + s + 1))*G4_ + (size_t)(tid>>4)*H_ + m*16 + (tid&15)];
    }

    if (!(own && s > 0)) {
      const unsigned long long* src =
          hb2 + ((size_t)(t & 1))*(B_*H_) + (size_t)b*H_ + tid*2;
      unsigned long long v0 = 0, v1 = 0;
      bool d0 = false, d1 = false;
      do {
        if (!d0) v0 = __hip_atomic_load(src,   __ATOMIC_RELAXED, __HIP_MEMORY_SCOPE_AGENT);
        if (!d1) v1 = __hip_atomic_load(src+1, __ATOMIC_RELAXED, __HIP_MEMORY_SCOPE_AGENT);
        d0 = d0 || ((unsigned)(v0 >> 32) == (unsigned)t);
        d1 = d1 || ((unsigned)(v1 >> 32) == (unsigned)t);
      } while (!(d0 && d1));
      union { unsigned u; float f; } a0u, a1u;
      a0u.u = (unsigned)v0; a1u.u = (unsigned)v1;
      hsh[p][2*tid]   = a0u.f;
      hsh[p][2*tid+1] = a1u.f;
    }
    __syncthreads();                               // the ONLY per-step barrier

    float xg0=0.f, xg1=0.f, xg2=0.f, xg3=0.f;
    if (q == 0) {
      xg0 = xpsh[p][c];      xg1 = xpsh[p][16+c];
      xg2 = xpsh[p][32+c];   xg3 = xpsh[p][48+c];
    }

    float a0=0.f, a1=0.f, a2=0.f, a3=0.f;
    #pragma unroll
    for (int k = 0; k < 8; ++k) {
      float4 h4 = *(const float4*)&hsh[p][q*4 + k*64];
      a0 = fmaf(w4[0][k].x,h4.x, fmaf(w4[0][k].y,h4.y, fmaf(w4[0][k].z,h4.z, fmaf(w4[0][k].w,h4.w, a0))));
      a1 = fmaf(w4[1][k].x,h4.x, fmaf(w4[1][k].y,h4.y, fmaf(w4[1][k].z,h4.z, fmaf(w4[1][k].w,h4.w, a1))));
      a2 = fmaf(w4[2][k].x,h4.x, fmaf(w4[2][k].y,h4.y, fmaf(w4[2][k].z,h4.z, fmaf(w4[2][k].w,h4.w, a2))));
      a3 = fmaf(w4[3][k].x,h4.x, fmaf(w4[3][k].y,h4.y, fmaf(w4[3][k].z,h4.z, fmaf(w4[3][k].w,h4.w, a3))));
    }
    #pragma unroll
    for (int msk = 1; msk < 16; msk <<= 1) {
      a0 += __shfl_xor(a0, msk, 64);
      a1 += __shfl_xor(a1, msk, 64);
      a2 += __shfl_xor(a2, msk, 64);
      a3 += __shfl_xor(a3, msk, 64);
    }

    if (q == 0) {
      float g0 = a0 + xg0, g1 = a1 + xg1, g2 = a2 + xg2, g3 = a3 + xg3;
      cc = sigm(g1)*cc + sigm(g0)*ftanh(g2);
      float hn = sigm(g3)*ftanh(cc);
      union { float f; unsigned u; } hu; hu.f = hn;
      unsigned long long wv =
          (((unsigned long long)(unsigned)(t + 1)) << 32) | (unsigned long long)hu.u;
      __hip_atomic_store(hb2 + ((size_t)((t+1) & 1))*(B_*H_) + (size_t)b*H_ + j, wv,
                         __ATOMIC_RELAXED, __HIP_MEMORY_SCOPE_AGENT);
      hsh[p^1][j] = hn;                  // self-bypass for next step
      enc_out[((size_t)b*L_ + t)*H_ + j] = hn;
      if (t == L_ - 1) hT[b*H_ + j] = hn;
    }
  }
  if (q == 0) cbuf[b*H_ + j] = cc;
}

// ---------------------------------------------------------------------------
// Fused launch: blocks [0,256) = recurrence chunk; blocks [256,256+ngemm) =
// concurrent GEMM (next chunk's Xproj, or ctx for finalized ENC rows).
// launch_bounds(256, 1): (256,4) capped VGPR at 64 and spilled the recur
// path (r13, WRITE_SIZE +44MB scratch). (256,1) => VGPR 92, no spill,
// fused dispatch 1195us (r14) — GEMM rides the latency-bound recurrence's
// idle SIMD slots essentially free. Recur blocks have the lowest IDs
// (dispatched resident first); GEMM blocks never wait on recur -> no
// deadlock possible, worst case lost overlap.
// ---------------------------------------------------------------------------
__global__ __launch_bounds__(256, 1) void fused_rg(
    const float* __restrict__ Xp, const float* __restrict__ Whh,
    float* __restrict__ enc_out, unsigned long long* __restrict__ hb2,
    float* __restrict__ cbuf, float* __restrict__ hT, int t0, int nsteps,
    const float* __restrict__ A, const float* __restrict__ W,
    const float* __restrict__ bias1, const float* __restrict__ bias2,
    float* __restrict__ C, int gN, int gK, int gCL, int gLtot, int gc0,
    int gCLc, int gLtotc, int gc0c, int gbx)
{
  if ((int)blockIdx.x < 256) {
    recur_body(Xp, Whh, enc_out, hb2, cbuf, hT, t0, nsteps);
  } else {
    const int b2 = (int)blockIdx.x - 256;
    gemm_body(A, W, bias1, bias2, C, gN, gK, gCL, gLtot, gc0,
              gCLc, gLtotc, gc0c, (b2 / gbx) * 128, (b2 % gbx) * 128);
  }
}

// ---------------------------------------------------------------------------
// out[b][n] = act( x1[b].W1[n,:K1] + (x2? x2[b].W2[n,:K2]) + bias1[n] (+bias2) )
// ---------------------------------------------------------------------------
__global__ __launch_bounds__(256) void dual_mv(
    const float* __restrict__ x1, const float* __restrict__ W1, int ld1, int K1,
    const float* __restrict__ x2, const float* __restrict__ W2, int ld2, int K2,
    const float* __restrict__ bias1, const float* __restrict__ bias2,
    float* __restrict__ out, int N, int act)
{
  const int w = blockIdx.x*4 + (threadIdx.x>>6);
  const int lane = threadIdx.x & 63;
  const int b = w / N, n = w % N;
  float s = 0.0f;
  for (int k = lane*4; k < K1; k += 256) {
    float4 xv = *(const float4*)(x1 + (size_t)b*K1 + k);
    float4 wv = *(const float4*)(W1 + (size_t)n*ld1 + k);
    s += xv.x*wv.x + xv.y*wv.y + xv.z*wv.z + xv.w*wv.w;
  }
  if (x2) {
    for (int k = lane*4; k < K2; k += 256) {
      float4 xv = *(const float4*)(x2 + (size_t)b*K2 + k);
      float4 wv = *(const float4*)(W2 + (size_t)n*ld2 + k);
      s += xv.x*wv.x + xv.y*wv.y + xv.z*wv.z + xv.w*wv.w;
    }
  }
  #pragma unroll
  for (int m=32; m>0; m>>=1) s += __shfl_xor(s, m, 64);
  if (lane == 0) {
    float r = s + bias1[n] + (bias2 ? bias2[n] : 0.0f);
    if (act) r = tanhf(r);
    out[(size_t)b*N + n] = r;
  }
}

__global__ void dec_cell(const float* __restrict__ g, float* __restrict__ c,
                         float* __restrict__ ht)
{
  int i = blockIdx.x*256 + threadIdx.x;     // 4096 threads
  int b = i >> 9, j = i & 511;
  const float* gb = g + (size_t)b*G4_;
  float gi_ = gb[j], gf = gb[H_+j], gg = gb[2*H_+j], go = gb[3*H_+j];
  float cc = c[i];
  cc = sigm(gf)*cc + sigm(gi_)*tanhf(gg);
  ht[i] = sigm(go)*tanhf(cc);
  c[i]  = cc;
}

__global__ __launch_bounds__(256) void dec_att(
    const float* __restrict__ inp, const float* __restrict__ ctx,
    const float* __restrict__ V, float* __restrict__ att)
{
  const int w = blockIdx.x*4 + (threadIdx.x>>6);  // w = b*L_ + l
  const int lane = threadIdx.x & 63;
  const int b = w >> 11;
  const float* cr = ctx + (size_t)w*H_;
  const float* ip = inp + (size_t)b*H_;
  float s = 0.0f;
  #pragma unroll
  for (int i=0;i<2;++i) {
    int k = lane*4 + i*256;
    float4 c4 = *(const float4*)(cr+k);
    float4 i4 = *(const float4*)(ip+k);
    float4 v4 = *(const float4*)(V+k);
    s += v4.x*tanhf(i4.x+c4.x) + v4.y*tanhf(i4.y+c4.y)
       + v4.z*tanhf(i4.z+c4.z) + v4.w*tanhf(i4.w+c4.w);
  }
  #pragma unroll
  for (int m=32; m>0; m>>=1) s += __shfl_xor(s, m, 64);
  if (lane == 0) att[w] = s;
}

__global__ __launch_bounds__(256) void dec_softmax(
    const float* __restrict__ att, const float* __restrict__ enc,
    int iter, int* __restrict__ chosen,
    float* __restrict__ out_alpha, float* __restrict__ out_ptr,
    float* __restrict__ x_next)
{
  const int b = blockIdx.x, tid = threadIdx.x;
  __shared__ float rv[256]; __shared__ int ri[256];
  __shared__ float s_mx, s_sum; __shared__ int s_idx;
  const int banned = iter ? chosen[b] : -1;
  float a[8]; float mx = -INFINITY;
  #pragma unroll
  for (int i=0;i<8;++i) {
    int l = (i<<8)+tid;
    float v = att[(size_t)b*L_ + l];
    if (l == banned) v = -INFINITY;
    a[i] = v; mx = fmaxf(mx, v);
  }
  rv[tid]=mx; __syncthreads();
  for (int s=128;s>0;s>>=1){ if (tid<s) rv[tid]=fmaxf(rv[tid],rv[tid+s]); __syncthreads(); }
  if (tid==0) s_mx = rv[0];
  __syncthreads();
  const float MX = s_mx;
  __syncthreads();
  float sum = 0.0f;
  #pragma unroll
  for (int i=0;i<8;++i) {
    int l = (i<<8)+tid;
    float pexp = (l == banned) ? 0.0f : expf(a[i]-MX);
    sum += pexp; a[i] = pexp;
  }
  rv[tid]=sum; __syncthreads();
  for (int s=128;s>0;s>>=1){ if (tid<s) rv[tid]+=rv[tid+s]; __syncthreads(); }
  if (tid==0) s_sum = rv[0];
  __syncthreads();
  const float inv = 1.0f/s_sum;
  __syncthreads();
  // argmax (first-occurrence on ties, matches jnp.argmax)
  float vb = -1.0f; int ib = 1<<30;
  #pragma unroll
  for (int i=0;i<8;++i) {
    int l = (i<<8)+tid;
    if (l != banned) { float v = a[i]; if (v > vb || (v == vb && l < ib)) { vb=v; ib=l; } }
  }
  rv[tid]=vb; ri[tid]=ib; __syncthreads();
  for (int s=128;s>0;s>>=1) {
    if (tid<s) {
      float v2=rv[tid+s]; int i2=ri[tid+s];
      if (v2 > rv[tid] || (v2 == rv[tid] && i2 < ri[tid])) { rv[tid]=v2; ri[tid]=i2; }
    }
    __syncthreads();
  }
  if (tid==0) {
    s_idx = ri[0];
    out_ptr[b*2+iter] = (float)ri[0];
    if (iter==0) chosen[b] = ri[0];
  }
  __syncthreads();
  #pragma unroll
  for (int i=0;i<8;++i) {
    int l = (i<<8)+tid;
    out_alpha[((size_t)b*2+iter)*L_ + l] = a[i]*inv;
  }
  const int idx = s_idx;
  for (int j=tid; j<H_; j+=256)
    x_next[(size_t)b*H_ + j] = enc[((size_t)b*L_ + idx)*H_ + j];
}

__global__ void dec_hidden1(const float* __restrict__ ctx, const float* __restrict__ alpha_all,
                            int iter, float* __restrict__ part)
{
  const int b = blockIdx.x >> 4, ch = blockIdx.x & 15;
  const int j = threadIdx.x;  // 512
  const float* al = alpha_all + ((size_t)b*2+iter)*L_ + ch*128;
  const float* cp = ctx + ((size_t)b*L_ + ch*128)*H_ + j;
  float s = 0.0f;
  for (int l=0; l<128; ++l) s += cp[(size_t)l*H_] * al[l];
  part[((size_t)b*16+ch)*H_ + j] = s;
}

__global__ void dec_hidden2(const float* __restrict__ part, float* __restrict__ hid)
{
  int i = blockIdx.x*256 + threadIdx.x;  // 4096
  int b = i >> 9, j = i & 511;
  float s = 0.0f;
  #pragma unroll
  for (int ch=0; ch<16; ++ch) s += part[((size_t)b*16+ch)*H_ + j];
  hid[i] = s;
}

// ---------------------------------------------------------------------------
extern "C" void kernel_launch(void* const* d_in, const int* in_sizes, int n_in,
                              void* d_out, int out_size, void* d_ws, size_t ws_size,
                              hipStream_t stream)
{
  const float* emb   = (const float*)d_in[0];
  const float* x0    = (const float*)d_in[1];
  const float* W_ih  = (const float*)d_in[2];
  const float* W_hh  = (const float*)d_in[3];
  const float* b_ih  = (const float*)d_in[4];
  const float* b_hh  = (const float*)d_in[5];
  const float* Wd_in = (const float*)d_in[6];
  const float* bd_in = (const float*)d_in[7];
  const float* Wd_hh = (const float*)d_in[8];
  const float* bd_hh = (const float*)d_in[9];
  const float* W_inp = (const float*)d_in[10];
  const float* b_inp = (const float*)d_in[11];
  const float* Wc    = (const float*)d_in[12];
  const float* bc    = (const float*)d_in[13];
  const float* V     = (const float*)d_in[14];
  const float* W_out = (const float*)d_in[15];
  const float* b_out = (const float*)d_in[16];

  const size_t BIG = 8388608;  // floats per XP/ENC buffer
  const size_t tail_floats = 8192*2 /*HB2*/ + 4096 + 4096 + 16384 + 4096*4 + 16384 + 65536 + 64;
  const bool dbuf = ws_size >= (3*BIG + tail_floats) * sizeof(float);

  float* ws  = (float*)d_ws;
  float* XPA = ws;                               // 8,388,608 floats; also CTX
  float* XPB = dbuf ? (XPA + BIG) : XPA;         // second Xproj buffer
  float* ENC = (dbuf ? XPB : XPA) + BIG;         // 8,388,608 floats
  unsigned long long* HB2 = (unsigned long long*)(ENC + BIG); // 8192 u64
  float* HB  = (float*)(HB2 + 8192);             // 4096 (h_T)
  float* CB  = HB + 4096;                        // 4096 (c state)
  float* DG  = CB + 4096;                        // 16384
  float* HT  = DG + 16384;                       // 4096
  float* INP = HT + 4096;                        // 4096
  float* ATT = INP + 4096;                       // 16384
  float* HID = ATT + 16384;                      // 4096
  float* XN  = HID + 4096;                       // 4096
  float* HD  = XN + 4096;                        // 4096
  float* PART = HD + 4096;                       // 65536
  int* CHOSEN = (int*)(PART + 65536);            // 8
  float* CTX = XPA;

  // zero tagged h buffer (tag0 = h0=0), h_T, c0 — contiguous region
  hipMemsetAsync(HB2, 0, 8192*sizeof(unsigned long long) + (4096+4096)*sizeof(float), stream);

  if (dbuf) {
    // 1. Xproj chunk0 -> XPA (exposed)
    gemm128<<<dim3(G4_/128, (B_*CL_)/128), 256, 0, stream>>>(
        emb, W_ih, b_ih, b_hh, XPA, G4_, E_, CL_, L_, 0*CL_, 1<<30, 0, 0);
    // 2-4. recur(chunk c) || Xproj(chunk c+1) into the other buffer
    float* xpsrc = XPA; float* xpdst = XPB;
    for (int c = 0; c < 3; ++c) {
      fused_rg<<<256 + 512, 256, 0, stream>>>(
          xpsrc, W_hh, ENC, HB2, CB, HB, c*CL_, CL_,
          emb, W_ih, b_ih, b_hh, xpdst, G4_, E_, CL_, L_, (c+1)*CL_,
          1<<30, 0, 0, /*gbx=*/16);
      float* tmp = xpsrc; xpsrc = xpdst; xpdst = tmp;
    }
    // 5. recur(chunk3) || ctx rows l<1536 (ENC chunks 0-2 finalized) -> CTX
    fused_rg<<<256 + 384, 256, 0, stream>>>(
        xpsrc, W_hh, ENC, HB2, CB, HB, 3*CL_, CL_,
        ENC, Wc, bc, nullptr, CTX, H_, H_, 1536, L_, 0,
        1536, L_, 0, /*gbx=*/4);
    // 6. ctx rows l in [1536,2048) (exposed, small)
    gemm128<<<dim3(H_/128, (B_*CL_)/128), 256, 0, stream>>>(
        ENC, Wc, bc, nullptr, CTX, H_, H_, CL_, L_, 1536, CL_, L_, 1536);
  } else {
    // serial fallback (= r5 schedule)
    for (int c = 0; c < 4; ++c) {
      gemm128<<<dim3(G4_/128, (B_*CL_)/128), 256, 0, stream>>>(
          emb, W_ih, b_ih, b_hh, XPA, G4_, E_, CL_, L_, c*CL_, 1<<30, 0, 0);
      fused_rg<<<256, 256, 0, stream>>>(
          XPA, W_hh, ENC, HB2, CB, HB, c*CL_, CL_,
          nullptr, nullptr, nullptr, nullptr, nullptr, 0, 0, 1, 1, 0, 1, 1, 0, 1);
    }
    gemm128<<<dim3(H_/128, (B_*L_)/128), 256, 0, stream>>>(
        ENC, Wc, bc, nullptr, CTX, H_, H_, L_, L_, 0, 1<<30, 0, 0);
  }

  // ---- decoder: 2 pointer steps ----
  float* out = (float*)d_out;
  const float* x_cur = x0;
  const float* h_cur = HB;
  for (int iter=0; iter<2; ++iter) {
    dual_mv<<<(B_*G4_)/4, 256, 0, stream>>>(x_cur, Wd_in, H_, H_,
                                            h_cur, Wd_hh, H_, H_,
                                            bd_in, bd_hh, DG, G4_, 0);
    dec_cell<<<16, 256, 0, stream>>>(DG, CB, HT);
    dual_mv<<<(B_*H_)/4, 256, 0, stream>>>(HT, W_inp, H_, H_,
                                           nullptr, nullptr, 0, 0,
                                           b_inp, nullptr, INP, H_, 0);
    dec_att<<<(B_*L_)/4, 256, 0, stream>>>(INP, CTX, V, ATT);
    dec_softmax<<<B_, 256, 0, stream>>>(ATT, ENC, iter, CHOSEN, out, out + 32768, XN);
    dec_hidden1<<<B_*16, 512, 0, stream>>>(CTX, out, iter, PART);
    dec_hidden2<<<16, 256, 0, stream>>>(PART, HID);
    dual_mv<<<(B_*H_)/4, 256, 0, stream>>>(HID, W_out, 2*H_, H_,
                                           HT, W_out + H_, 2*H_, H_,
                                           b_out, nullptr, HD, H_, 1);
    x_cur = XN; h_cur = HD;
  }
}